// Round 3
// baseline (402.600 us; speedup 1.0000x reference)
//
#include <hip/hip_runtime.h>

#define B_ 128
#define N_ 64
#define T_ 1000
#define H_ 16
#define TPAD 1014   // 7 zeros + 1000 + 7 zeros

// ---------------- A: energy[b,i] = var(x[b,0,i,:], ddof=1) ----------------
__global__ __launch_bounds__(256) void k_energy(const float* __restrict__ x, float* __restrict__ energy) {
    int row = blockIdx.x;                       // b*64 + i
    const float* xr = x + (size_t)row * T_;
    float s = 0.f, s2 = 0.f;
    for (int t4 = threadIdx.x; t4 < 250; t4 += 256) {
        float4 v = ((const float4*)xr)[t4];
        s += v.x + v.y + v.z + v.w;
        s2 += v.x*v.x + v.y*v.y + v.z*v.z + v.w*v.w;
    }
    __shared__ float r1[256], r2[256];
    r1[threadIdx.x] = s; r2[threadIdx.x] = s2;
    __syncthreads();
    for (int off = 128; off > 0; off >>= 1) {
        if (threadIdx.x < off) {
            r1[threadIdx.x] += r1[threadIdx.x + off];
            r2[threadIdx.x] += r2[threadIdx.x + off];
        }
        __syncthreads();
    }
    if (threadIdx.x == 0) {
        float S = r1[0], S2 = r2[0];
        energy[row] = (S2 - S * S / (float)T_) / (float)(T_ - 1);
    }
}

// ---------------- B: attn + diag-mask + softmax -> w (written to d_out) ----
__global__ void k_attn_softmax(const float* __restrict__ energy,
                               const float* __restrict__ q_w, const float* __restrict__ q_b,
                               const float* __restrict__ k_w, const float* __restrict__ k_b,
                               float* __restrict__ wout) {
    int row = blockIdx.x;                       // b*64 + i
    int b = row >> 6, i = row & 63;
    int j = threadIdx.x;                        // 64 threads
    float ei = energy[b * 64 + i];
    float ej = energy[b * 64 + j];
    float a = 0.f;
    #pragma unroll
    for (int h = 0; h < H_; ++h)
        a += (ei * q_w[h] + q_b[h]) * (ej * k_w[h] + k_b[h]);
    a *= 0.25f;                                 // H^(-1/2), H=16
    if (j == i) a = -1e9f;
    float m = a;
    #pragma unroll
    for (int mask = 32; mask; mask >>= 1) m = fmaxf(m, __shfl_xor(m, mask));
    float p = __expf(a - m);
    float s = p;
    #pragma unroll
    for (int mask = 32; mask; mask >>= 1) s += __shfl_xor(s, mask);
    wout[(size_t)row * 64 + j] = p / s;
}

// ---------------- C: z_gcn = w @ xs + x  (register-tiled 8x4) --------------
#define ZTC 128
__global__ __launch_bounds__(256) void k_zgcn(const float* __restrict__ wmat,
        const float* __restrict__ x, float* __restrict__ zg) {
    int b = blockIdx.y;
    int t0 = blockIdx.x * ZTC;                  // 8 chunks: 0,128,...,896
    __shared__ __attribute__((aligned(16))) float wsh[64 * 64];
    __shared__ __attribute__((aligned(16))) float xs[64][ZTC];
    const float4* wb4 = (const float4*)(wmat + (size_t)b * 4096);
    float4* wsh4 = (float4*)wsh;
    for (int i = threadIdx.x; i < 1024; i += 256) wsh4[i] = wb4[i];
    const float* xb = x + (size_t)b * 64 * T_;
    for (int i = threadIdx.x; i < 2048; i += 256) {
        int jj = i >> 5;                        // row (32 float4 per row)
        int c4 = i & 31;
        int tt = t0 + c4 * 4;
        float4 val;
        if (tt + 3 < T_) val = *(const float4*)(xb + jj * T_ + tt);
        else {
            val.x = (tt     < T_) ? xb[jj * T_ + tt]     : 0.f;
            val.y = (tt + 1 < T_) ? xb[jj * T_ + tt + 1] : 0.f;
            val.z = (tt + 2 < T_) ? xb[jj * T_ + tt + 2] : 0.f;
            val.w = (tt + 3 < T_) ? xb[jj * T_ + tt + 3] : 0.f;
        }
        *(float4*)&xs[jj][c4 * 4] = val;
    }
    __syncthreads();
    int gi = threadIdx.x >> 5;                  // 8 ii-groups
    int gt = threadIdx.x & 31;                  // 32 tt-groups
    int ii0 = gi * 8, tt0 = gt * 4;
    float4 acc[8];
    #pragma unroll
    for (int r = 0; r < 8; ++r) acc[r] = float4{0.f, 0.f, 0.f, 0.f};
    for (int jj = 0; jj < 64; ++jj) {
        float4 xv = *(const float4*)&xs[jj][tt0];
        #pragma unroll
        for (int r = 0; r < 8; ++r) {
            float wv = wsh[(ii0 + r) * 64 + jj];
            acc[r].x += wv * xv.x; acc[r].y += wv * xv.y;
            acc[r].z += wv * xv.z; acc[r].w += wv * xv.w;
        }
    }
    int tt = t0 + tt0;
    #pragma unroll
    for (int r = 0; r < 8; ++r) {
        float4 res = *(const float4*)&xs[ii0 + r][tt0];
        acc[r].x += res.x; acc[r].y += res.y; acc[r].z += res.z; acc[r].w += res.w;
        float* dst = zg + (size_t)b * 64 * T_ + (size_t)(ii0 + r) * T_;
        if (tt + 3 < T_) {
            *(float4*)(dst + tt) = acc[r];
        } else {
            if (tt     < T_) dst[tt]     = acc[r].x;
            if (tt + 1 < T_) dst[tt + 1] = acc[r].y;
            if (tt + 2 < T_) dst[tt + 2] = acc[r].z;
            if (tt + 3 < T_) dst[tt + 3] = acc[r].w;
        }
    }
}

// ---------------- D1: autocorr lags 0..14 + total sum ----------------------
// stats[0..14] = A[d] = sum_rows sum_i z[i]*z[i+d];  stats[15] = SA = sum z
__global__ __launch_bounds__(256) void k_autocorr(const float* __restrict__ zg, double* __restrict__ stats) {
    int th = blockIdx.x * 256 + threadIdx.x;
    int row = th >> 3;
    int t0 = (th & 7) * 125;
    const float* zr = zg + (size_t)row * T_;
    float win[15];
    #pragma unroll
    for (int k = 0; k < 14; ++k) win[k] = zr[t0 + k];   // max idx 888 < 1000
    float acc[15];
    #pragma unroll
    for (int k = 0; k < 15; ++k) acc[k] = 0.f;
    float s1 = 0.f;
    int t = t0;
    #define AW(u,k) win[(((u)+(k)) % 15)]
    #define ASTEP(u) { \
        int j = t + (u) + 14; \
        AW(u,14) = (j < T_) ? zr[j] : 0.f; \
        float z0 = AW(u,0); s1 += z0; \
        acc[0]  += z0*AW(u,0);  acc[1]  += z0*AW(u,1);  acc[2]  += z0*AW(u,2); \
        acc[3]  += z0*AW(u,3);  acc[4]  += z0*AW(u,4);  acc[5]  += z0*AW(u,5); \
        acc[6]  += z0*AW(u,6);  acc[7]  += z0*AW(u,7);  acc[8]  += z0*AW(u,8); \
        acc[9]  += z0*AW(u,9);  acc[10] += z0*AW(u,10); acc[11] += z0*AW(u,11); \
        acc[12] += z0*AW(u,12); acc[13] += z0*AW(u,13); acc[14] += z0*AW(u,14); }
    for (int mi = 0; mi < 8; ++mi) {            // 8*15 = 120 steps
        ASTEP(0) ASTEP(1) ASTEP(2) ASTEP(3) ASTEP(4)
        ASTEP(5) ASTEP(6) ASTEP(7) ASTEP(8) ASTEP(9)
        ASTEP(10) ASTEP(11) ASTEP(12) ASTEP(13) ASTEP(14)
        t += 15;
    }
    ASTEP(0) ASTEP(1) ASTEP(2) ASTEP(3) ASTEP(4)   // 125 total
    #undef ASTEP
    #undef AW
    __shared__ float red[256][17];
    #pragma unroll
    for (int k = 0; k < 15; ++k) red[threadIdx.x][k] = acc[k];
    red[threadIdx.x][15] = s1;
    __syncthreads();
    for (int off = 128; off > 0; off >>= 1) {
        if (threadIdx.x < off)
            for (int k = 0; k < 16; ++k) red[threadIdx.x][k] += red[threadIdx.x + off][k];
        __syncthreads();
    }
    if (threadIdx.x < 16) atomicAdd(&stats[threadIdx.x], (double)red[0][threadIdx.x]);
}

// ---------------- D2: boundary-correction sums (LDS-staged) ----------------
// stats[16+v]: v<105 HP[i][d]=sum z[i]z[i+d] (i=0..6,d=0..14); v<133 TP (tail pairs);
// v<140 prefix sums 0..m (m=0..6); v<147 suffix sums m..999 (m=993..999)
#define EROWS 256
__global__ __launch_bounds__(256) void k_edges(const float* __restrict__ zg, double* __restrict__ stats) {
    __shared__ float head[EROWS][21];
    __shared__ float tail[EROWS][7];
    int row0 = blockIdx.x * EROWS;
    for (int idx = threadIdx.x; idx < EROWS * 21; idx += 256) {
        int r = idx / 21, c = idx - r * 21;
        head[r][c] = zg[(size_t)(row0 + r) * T_ + c];
    }
    for (int idx = threadIdx.x; idx < EROWS * 7; idx += 256) {
        int r = idx / 7, c = idx - r * 7;
        tail[r][c] = zg[(size_t)(row0 + r) * T_ + 993 + c];
    }
    __syncthreads();
    int v = threadIdx.x;
    if (v >= 147) return;
    int mode, ia, ib;
    if (v < 105) { mode = 0; ia = v / 15; ib = ia + (v % 15); }          // head pair
    else if (v < 133) {
        int idx = v - 105; int i = 0, len = 7;                            // tail pair
        while (idx >= len) { idx -= len; ++i; --len; }
        mode = 2; ia = i; ib = i + idx;                                   // tail-local idx
    }
    else if (v < 140) { mode = 1; ia = 0; ib = v - 133; }                 // prefix head
    else { mode = 3; ia = v - 140; ib = 6; }                              // suffix tail-local
    double acc = 0.0;
    for (int r = 0; r < EROWS; ++r) {
        float val;
        if (mode == 0)      val = head[r][ia] * head[r][ib];
        else if (mode == 2) val = tail[r][ia] * tail[r][ib];
        else if (mode == 1) { val = 0.f; for (int i = ia; i <= ib; ++i) val += head[r][i]; }
        else                { val = 0.f; for (int i = ia; i <= ib; ++i) val += tail[r][i]; }
        acc += (double)val;
    }
    atomicAdd(&stats[16 + v], acc);
}

// ---------------- E: finalize BN -> folded taps + shift --------------------
__global__ void k_finalize2(const double* __restrict__ stats, const float* __restrict__ conv_w,
                            const float* __restrict__ gamma, const float* __restrict__ beta,
                            float* __restrict__ scsh) {
    int h = threadIdx.x;
    if (h >= 16) return;
    const double M = (double)(B_ * N_) * (double)T_;
    double w[15];
    for (int k = 0; k < 15; ++k) w[k] = (double)conv_w[h * 15 + k];
    double SA = stats[15];
    const double* HP  = stats + 16;
    const double* TP  = stats + 16 + 105;
    const double* PRE = stats + 16 + 133;
    const double* SUF = stats + 16 + 140;
    // mean of conv output o (without conv_b)
    double so = 0.0;
    for (int k = 0; k < 15; ++k) {
        double U = SA;
        if (k < 7)      U -= SUF[k];        // suffix from 993+k
        else if (k > 7) U -= PRE[k - 8];    // prefix 0..k-8
        so += w[k] * U;
    }
    double mean_o = so / M;
    // second moment
    double q = 0.0;
    for (int k = 0; k < 15; ++k)
    for (int k2 = 0; k2 < 15; ++k2) {
        int a = (k < k2) ? k : k2;
        int d = (k < k2) ? (k2 - k) : (k - k2);
        double G = stats[d];
        if (a >= 8)
            for (int i = 0; i <= a - 8; ++i) G -= HP[i * 15 + d];
        if (a + d <= 6)
            for (int i = a + 993; i <= 999 - d; ++i) {
                int ip = i - 993;
                G -= TP[ip * 7 - ip * (ip - 1) / 2 + d];
            }
        q += w[k] * w[k2] * G;
    }
    double var = q / M - mean_o * mean_o;
    double sc = (double)gamma[h] / sqrt(var + 1e-5);
    scsh[240 + h] = (float)((double)beta[h] - mean_o * sc);
    for (int k = 0; k < 15; ++k) scsh[h * 15 + k] = (float)(w[k] * sc);
}

// ---------------- F: conv(+BN folded) + ELU + LIF scan -> firing rate ------
__global__ __launch_bounds__(256) void k_scan(const float* __restrict__ zg,
        const float* __restrict__ scsh, float* __restrict__ zfeat) {
    __shared__ float rows[16 * TPAD];
    int h = threadIdx.x & 15, r = threadIdx.x >> 4;
    int row0 = blockIdx.x * 16;
    for (int idx = threadIdx.x; idx < 16 * TPAD; idx += 256) {
        int rr = idx / TPAD, j = idx - rr * TPAD;
        float ld = 0.f;
        if (j >= 7 && j < 7 + T_) ld = zg[(size_t)(row0 + rr) * T_ + (j - 7)];
        rows[idx] = ld;
    }
    __syncthreads();
    float tap[15];
    #pragma unroll
    for (int k = 0; k < 15; ++k) tap[k] = scsh[h * 15 + k];
    float sh = scsh[240 + h];
    const float* p = rows + r * TPAD;
    float win[15];
    #pragma unroll
    for (int k = 0; k < 14; ++k) win[k] = p[k];
    float v = 0.f, cnt = 0.f;
    int t = 0;
    #define SW(u,k) win[(((u)+(k)) % 15)]
    #define STEP(u) { \
        SW(u,14) = p[t + (u) + 14]; \
        float o0 = tap[0]*SW(u,0)  + tap[1]*SW(u,1)   + tap[2]*SW(u,2)   + tap[3]*SW(u,3)   + tap[4]*SW(u,4); \
        float o1 = tap[5]*SW(u,5)  + tap[6]*SW(u,6)   + tap[7]*SW(u,7)   + tap[8]*SW(u,8)   + tap[9]*SW(u,9); \
        float o2 = tap[10]*SW(u,10) + tap[11]*SW(u,11) + tap[12]*SW(u,12) + tap[13]*SW(u,13) + tap[14]*SW(u,14); \
        float zf = (o0 + o1 + o2) + sh; \
        float a = zf > 0.f ? zf : (__expf(zf) - 1.f); \
        v = 0.5f * v + a; \
        float s = (v > 0.5f) ? 1.f : 0.f; \
        cnt += s; v -= 0.5f * s; }
    for (int mi = 0; mi < 66; ++mi) {           // 66*15 = 990
        STEP(0) STEP(1) STEP(2) STEP(3) STEP(4)
        STEP(5) STEP(6) STEP(7) STEP(8) STEP(9)
        STEP(10) STEP(11) STEP(12) STEP(13) STEP(14)
        t += 15;
    }
    STEP(0) STEP(1) STEP(2) STEP(3) STEP(4)     // tail 990..999
    STEP(5) STEP(6) STEP(7) STEP(8) STEP(9)
    #undef STEP
    #undef SW
    int row = row0 + r;
    int b = row >> 6, i = row & 63;
    zfeat[(size_t)b * 1024 + h * 64 + i] = cnt * (1.0f / (float)T_);
}

// ---------------- G: logits = z_feat @ fc_w.T + fc_b -----------------------
__global__ __launch_bounds__(256) void k_fc(const float* __restrict__ zfeat, const float* __restrict__ fc_w,
                     const float* __restrict__ fc_b, float* __restrict__ logits) {
    int b = blockIdx.x;
    const float* zf = zfeat + (size_t)b * 1024;
    float a0 = 0.f, a1 = 0.f, a2 = 0.f, a3 = 0.f;
    for (int f = threadIdx.x; f < 1024; f += 256) {
        float z = zf[f];
        a0 += z * fc_w[f];
        a1 += z * fc_w[1024 + f];
        a2 += z * fc_w[2048 + f];
        a3 += z * fc_w[3072 + f];
    }
    __shared__ float red[4][256];
    red[0][threadIdx.x] = a0; red[1][threadIdx.x] = a1;
    red[2][threadIdx.x] = a2; red[3][threadIdx.x] = a3;
    __syncthreads();
    for (int off = 128; off > 0; off >>= 1) {
        if (threadIdx.x < off) {
            red[0][threadIdx.x] += red[0][threadIdx.x + off];
            red[1][threadIdx.x] += red[1][threadIdx.x + off];
            red[2][threadIdx.x] += red[2][threadIdx.x + off];
            red[3][threadIdx.x] += red[3][threadIdx.x + off];
        }
        __syncthreads();
    }
    if (threadIdx.x < 4) logits[b * 4 + threadIdx.x] = red[threadIdx.x][0] + fc_b[threadIdx.x];
}

extern "C" void kernel_launch(void* const* d_in, const int* in_sizes, int n_in,
                              void* d_out, int out_size, void* d_ws, size_t ws_size,
                              hipStream_t stream) {
    (void)in_sizes; (void)n_in; (void)out_size; (void)ws_size;
    const float* x      = (const float*)d_in[0];
    const float* q_w    = (const float*)d_in[1];
    const float* q_b    = (const float*)d_in[2];
    const float* k_w    = (const float*)d_in[3];
    const float* k_b    = (const float*)d_in[4];
    const float* conv_w = (const float*)d_in[5];
    const float* bn_g   = (const float*)d_in[7];
    const float* bn_b   = (const float*)d_in[8];
    const float* fc_w   = (const float*)d_in[9];
    const float* fc_b   = (const float*)d_in[10];

    float* out    = (float*)d_out;
    float* logits = out;                        // 128*4
    float* zfeat  = out + 512;                  // 128*1024
    float* wmat   = out + 512 + 131072;         // 128*64*64

    char* ws      = (char*)d_ws;
    float* energy = (float*)ws;                               // 8192 f32
    float* zg     = (float*)(ws + 32768);                     // 8.192M f32
    double* stats = (double*)(ws + 32768 + 32768000);         // 163 f64
    float* scsh   = (float*)(ws + 32768 + 32768000 + 2048);   // 256 f32

    k_energy<<<B_ * N_, 256, 0, stream>>>(x, energy);
    k_attn_softmax<<<B_ * N_, 64, 0, stream>>>(energy, q_w, q_b, k_w, k_b, wmat);
    k_zgcn<<<dim3(8, B_), 256, 0, stream>>>(wmat, x, zg);
    hipMemsetAsync(stats, 0, 163 * sizeof(double), stream);
    k_autocorr<<<256, 256, 0, stream>>>(zg, stats);
    k_edges<<<32, 256, 0, stream>>>(zg, stats);
    k_finalize2<<<1, 64, 0, stream>>>(stats, conv_w, bn_g, bn_b, scsh);
    k_scan<<<B_ * N_ / 16, 256, 0, stream>>>(zg, scsh, zfeat);
    k_fc<<<B_, 256, 0, stream>>>(zfeat, fc_w, fc_b, logits);
}

// Round 4
// 251.665 us; speedup vs baseline: 1.5997x; 1.5997x over previous
//
#include <hip/hip_runtime.h>

#define B_ 128
#define N_ 64
#define T_ 1000
#define H_ 16

// ---------------- A: energy[b,i] = var(x[b,0,i,:], ddof=1) ----------------
__global__ __launch_bounds__(256) void k_energy(const float* __restrict__ x, float* __restrict__ energy) {
    int row = blockIdx.x;                       // b*64 + i
    const float* xr = x + (size_t)row * T_;
    float s = 0.f, s2 = 0.f;
    for (int t4 = threadIdx.x; t4 < 250; t4 += 256) {
        float4 v = ((const float4*)xr)[t4];
        s += v.x + v.y + v.z + v.w;
        s2 += v.x*v.x + v.y*v.y + v.z*v.z + v.w*v.w;
    }
    __shared__ float r1[256], r2[256];
    r1[threadIdx.x] = s; r2[threadIdx.x] = s2;
    __syncthreads();
    for (int off = 128; off > 0; off >>= 1) {
        if (threadIdx.x < off) {
            r1[threadIdx.x] += r1[threadIdx.x + off];
            r2[threadIdx.x] += r2[threadIdx.x + off];
        }
        __syncthreads();
    }
    if (threadIdx.x == 0) {
        float S = r1[0], S2 = r2[0];
        energy[row] = (S2 - S * S / (float)T_) / (float)(T_ - 1);
    }
}

// ---------------- B: attn + diag-mask + softmax -> w (written to d_out) ----
__global__ void k_attn_softmax(const float* __restrict__ energy,
                               const float* __restrict__ q_w, const float* __restrict__ q_b,
                               const float* __restrict__ k_w, const float* __restrict__ k_b,
                               float* __restrict__ wout) {
    int row = blockIdx.x;                       // b*64 + i
    int b = row >> 6, i = row & 63;
    int j = threadIdx.x;                        // 64 threads
    float ei = energy[b * 64 + i];
    float ej = energy[b * 64 + j];
    float a = 0.f;
    #pragma unroll
    for (int h = 0; h < H_; ++h)
        a += (ei * q_w[h] + q_b[h]) * (ej * k_w[h] + k_b[h]);
    a *= 0.25f;                                 // H^(-1/2), H=16
    if (j == i) a = -1e9f;
    float m = a;
    #pragma unroll
    for (int mask = 32; mask; mask >>= 1) m = fmaxf(m, __shfl_xor(m, mask));
    float p = __expf(a - m);
    float s = p;
    #pragma unroll
    for (int mask = 32; mask; mask >>= 1) s += __shfl_xor(s, mask);
    wout[(size_t)row * 64 + j] = p / s;
}

// ---------------- C: z_gcn = w @ xs + x  (register-tiled 8x4) --------------
#define ZTC 128
__global__ __launch_bounds__(256) void k_zgcn(const float* __restrict__ wmat,
        const float* __restrict__ x, float* __restrict__ zg) {
    int b = blockIdx.y;
    int t0 = blockIdx.x * ZTC;                  // 8 chunks: 0,128,...,896
    __shared__ __attribute__((aligned(16))) float wsh[64 * 64];
    __shared__ __attribute__((aligned(16))) float xs[64][ZTC];
    const float4* wb4 = (const float4*)(wmat + (size_t)b * 4096);
    float4* wsh4 = (float4*)wsh;
    for (int i = threadIdx.x; i < 1024; i += 256) wsh4[i] = wb4[i];
    const float* xb = x + (size_t)b * 64 * T_;
    for (int i = threadIdx.x; i < 2048; i += 256) {
        int jj = i >> 5;                        // row (32 float4 per row)
        int c4 = i & 31;
        int tt = t0 + c4 * 4;
        float4 val;
        if (tt + 3 < T_) val = *(const float4*)(xb + jj * T_ + tt);
        else {
            val.x = (tt     < T_) ? xb[jj * T_ + tt]     : 0.f;
            val.y = (tt + 1 < T_) ? xb[jj * T_ + tt + 1] : 0.f;
            val.z = (tt + 2 < T_) ? xb[jj * T_ + tt + 2] : 0.f;
            val.w = (tt + 3 < T_) ? xb[jj * T_ + tt + 3] : 0.f;
        }
        *(float4*)&xs[jj][c4 * 4] = val;
    }
    __syncthreads();
    int gi = threadIdx.x >> 5;                  // 8 ii-groups
    int gt = threadIdx.x & 31;                  // 32 tt-groups
    int ii0 = gi * 8, tt0 = gt * 4;
    float4 acc[8];
    #pragma unroll
    for (int r = 0; r < 8; ++r) acc[r] = float4{0.f, 0.f, 0.f, 0.f};
    for (int jj = 0; jj < 64; ++jj) {
        float4 xv = *(const float4*)&xs[jj][tt0];
        #pragma unroll
        for (int r = 0; r < 8; ++r) {
            float wv = wsh[(ii0 + r) * 64 + jj];
            acc[r].x += wv * xv.x; acc[r].y += wv * xv.y;
            acc[r].z += wv * xv.z; acc[r].w += wv * xv.w;
        }
    }
    int tt = t0 + tt0;
    #pragma unroll
    for (int r = 0; r < 8; ++r) {
        float4 res = *(const float4*)&xs[ii0 + r][tt0];
        acc[r].x += res.x; acc[r].y += res.y; acc[r].z += res.z; acc[r].w += res.w;
        float* dst = zg + (size_t)b * 64 * T_ + (size_t)(ii0 + r) * T_;
        if (tt + 3 < T_) {
            *(float4*)(dst + tt) = acc[r];
        } else {
            if (tt     < T_) dst[tt]     = acc[r].x;
            if (tt + 1 < T_) dst[tt + 1] = acc[r].y;
            if (tt + 2 < T_) dst[tt + 2] = acc[r].z;
            if (tt + 3 < T_) dst[tt + 3] = acc[r].w;
        }
    }
}

// ---------------- D1: autocorr lags 0..14 + total sum ----------------------
// stats[0..14] = A[d] = sum_rows sum_i z[i]*z[i+d];  stats[15] = SA = sum z
__global__ __launch_bounds__(256) void k_autocorr(const float* __restrict__ zg, double* __restrict__ stats) {
    int th = blockIdx.x * 256 + threadIdx.x;
    int row = th >> 3;
    int t0 = (th & 7) * 125;
    const float* zr = zg + (size_t)row * T_;
    float win[15];
    #pragma unroll
    for (int k = 0; k < 14; ++k) win[k] = zr[t0 + k];   // max idx 888 < 1000
    float acc[15];
    #pragma unroll
    for (int k = 0; k < 15; ++k) acc[k] = 0.f;
    float s1 = 0.f;
    int t = t0;
    #define AW(u,k) win[(((u)+(k)) % 15)]
    #define ASTEP(u) { \
        int j = t + (u) + 14; \
        AW(u,14) = (j < T_) ? zr[j] : 0.f; \
        float z0 = AW(u,0); s1 += z0; \
        acc[0]  += z0*AW(u,0);  acc[1]  += z0*AW(u,1);  acc[2]  += z0*AW(u,2); \
        acc[3]  += z0*AW(u,3);  acc[4]  += z0*AW(u,4);  acc[5]  += z0*AW(u,5); \
        acc[6]  += z0*AW(u,6);  acc[7]  += z0*AW(u,7);  acc[8]  += z0*AW(u,8); \
        acc[9]  += z0*AW(u,9);  acc[10] += z0*AW(u,10); acc[11] += z0*AW(u,11); \
        acc[12] += z0*AW(u,12); acc[13] += z0*AW(u,13); acc[14] += z0*AW(u,14); }
    for (int mi = 0; mi < 8; ++mi) {            // 8*15 = 120 steps
        ASTEP(0) ASTEP(1) ASTEP(2) ASTEP(3) ASTEP(4)
        ASTEP(5) ASTEP(6) ASTEP(7) ASTEP(8) ASTEP(9)
        ASTEP(10) ASTEP(11) ASTEP(12) ASTEP(13) ASTEP(14)
        t += 15;
    }
    ASTEP(0) ASTEP(1) ASTEP(2) ASTEP(3) ASTEP(4)   // 125 total
    #undef ASTEP
    #undef AW
    __shared__ float red[256][17];
    #pragma unroll
    for (int k = 0; k < 15; ++k) red[threadIdx.x][k] = acc[k];
    red[threadIdx.x][15] = s1;
    __syncthreads();
    for (int off = 128; off > 0; off >>= 1) {
        if (threadIdx.x < off)
            for (int k = 0; k < 16; ++k) red[threadIdx.x][k] += red[threadIdx.x + off][k];
        __syncthreads();
    }
    if (threadIdx.x < 16) atomicAdd(&stats[threadIdx.x], (double)red[0][threadIdx.x]);
}

// ---------------- D2: boundary corrections — one stat per block ------------
// stats[16+v]: v<105 HP[i][d]=sum z[i]z[i+d] (i=0..6,d=0..14); v<133 TP (tail pairs);
// v<140 prefix sums 0..m (m=0..6); v<147 suffix sums m..999 (m=993..999)
__global__ __launch_bounds__(256) void k_edges(const float* __restrict__ zg, double* __restrict__ stats) {
    int v = blockIdx.x;                         // 0..146, uniform per block
    int mode, ia, ib;
    if (v < 105) { mode = 0; ia = v / 15; ib = ia + (v % 15); }          // head pair (global idx)
    else if (v < 133) {
        int idx = v - 105; int i = 0, len = 7;
        while (idx >= len) { idx -= len; ++i; --len; }
        mode = 2; ia = i; ib = i + idx;                                   // tail-local idx
    }
    else if (v < 140) { mode = 1; ia = 0; ib = v - 133; }                 // prefix head
    else { mode = 3; ia = v - 140; ib = 6; }                              // suffix tail-local
    double acc = 0.0;
    for (int it = 0; it < 32; ++it) {
        int row = it * 256 + threadIdx.x;
        const float* zr = zg + (size_t)row * T_;
        float val;
        if (mode == 0)      val = zr[ia] * zr[ib];
        else if (mode == 2) val = zr[993 + ia] * zr[993 + ib];
        else if (mode == 1) { val = 0.f; for (int i = ia; i <= ib; ++i) val += zr[i]; }
        else                { val = 0.f; for (int i = ia; i <= ib; ++i) val += zr[993 + i]; }
        acc += (double)val;
    }
    __shared__ double red[256];
    red[threadIdx.x] = acc;
    __syncthreads();
    for (int off = 128; off > 0; off >>= 1) {
        if (threadIdx.x < off) red[threadIdx.x] += red[threadIdx.x + off];
        __syncthreads();
    }
    if (threadIdx.x == 0) stats[16 + v] = red[0];
}

// ---------------- E: finalize BN -> folded taps + shift --------------------
__global__ void k_finalize2(const double* __restrict__ stats, const float* __restrict__ conv_w,
                            const float* __restrict__ gamma, const float* __restrict__ beta,
                            float* __restrict__ scsh) {
    int h = threadIdx.x;
    if (h >= 16) return;
    const double M = (double)(B_ * N_) * (double)T_;
    double w[15];
    for (int k = 0; k < 15; ++k) w[k] = (double)conv_w[h * 15 + k];
    double SA = stats[15];
    const double* HP  = stats + 16;
    const double* TP  = stats + 16 + 105;
    const double* PRE = stats + 16 + 133;
    const double* SUF = stats + 16 + 140;
    // mean of conv output o (without conv_b)
    double so = 0.0;
    for (int k = 0; k < 15; ++k) {
        double U = SA;
        if (k < 7)      U -= SUF[k];        // suffix from 993+k
        else if (k > 7) U -= PRE[k - 8];    // prefix 0..k-8
        so += w[k] * U;
    }
    double mean_o = so / M;
    // second moment
    double q = 0.0;
    for (int k = 0; k < 15; ++k)
    for (int k2 = 0; k2 < 15; ++k2) {
        int a = (k < k2) ? k : k2;
        int d = (k < k2) ? (k2 - k) : (k - k2);
        double G = stats[d];
        if (a >= 8)
            for (int i = 0; i <= a - 8; ++i) G -= HP[i * 15 + d];
        if (a + d <= 6)
            for (int i = a + 993; i <= 999 - d; ++i) {
                int ip = i - 993;
                G -= TP[ip * 7 - ip * (ip - 1) / 2 + d];
            }
        q += w[k] * w[k2] * G;
    }
    double var = q / M - mean_o * mean_o;
    double sc = (double)gamma[h] / sqrt(var + 1e-5);
    scsh[240 + h] = (float)((double)beta[h] - mean_o * sc);
    for (int k = 0; k < 15; ++k) scsh[h * 15 + k] = (float)(w[k] * sc);
}

// ------- F: conv(+BN folded) + ELU + LIF scan, chunked double-buffered -----
// 16 rows x 16 ch per block; T in 8 chunks of 125; LDS 2 x 16 x 140 floats.
__global__ __launch_bounds__(256, 4) void k_scan(const float* __restrict__ zg,
        const float* __restrict__ scsh, float* __restrict__ zfeat) {
    __shared__ float buf[2][16][140];
    int h = threadIdx.x & 15, r = threadIdx.x >> 4;
    int row0 = blockIdx.x * 16;
    float tap[15];
    #pragma unroll
    for (int k = 0; k < 15; ++k) tap[k] = scsh[h * 15 + k];
    float sh = scsh[240 + h];

    #define STAGE(cc, db) { \
        int g0 = 125 * (cc) - 7; \
        for (int idx = threadIdx.x; idx < 16 * 139; idx += 256) { \
            int rr = idx / 139, u = idx - rr * 139; \
            int g = g0 + u; \
            float val = 0.f; \
            if (g >= 0 && g < T_) val = zg[(size_t)(row0 + rr) * T_ + g]; \
            buf[db][rr][u] = val; \
        } }

    float v = 0.f, cnt = 0.f;
    STAGE(0, 0)
    __syncthreads();
    for (int c = 0; c < 8; ++c) {
        if (c < 7) STAGE(c + 1, (c + 1) & 1)
        const float* p = &buf[c & 1][r][0];
        float win[15];
        #pragma unroll
        for (int k = 0; k < 14; ++k) win[k] = p[k];
        int t = 0;
        #define SW(u,k) win[(((u)+(k)) % 15)]
        #define STEP(u) { \
            SW(u,14) = p[t + (u) + 14]; \
            float o0 = tap[0]*SW(u,0)  + tap[1]*SW(u,1)   + tap[2]*SW(u,2)   + tap[3]*SW(u,3)   + tap[4]*SW(u,4); \
            float o1 = tap[5]*SW(u,5)  + tap[6]*SW(u,6)   + tap[7]*SW(u,7)   + tap[8]*SW(u,8)   + tap[9]*SW(u,9); \
            float o2 = tap[10]*SW(u,10) + tap[11]*SW(u,11) + tap[12]*SW(u,12) + tap[13]*SW(u,13) + tap[14]*SW(u,14); \
            float zf = (o0 + o1 + o2) + sh; \
            float a = zf > 0.f ? zf : (__expf(zf) - 1.f); \
            v = 0.5f * v + a; \
            float s = (v > 0.5f) ? 1.f : 0.f; \
            cnt += s; v -= 0.5f * s; }
        for (int mi = 0; mi < 8; ++mi) {        // 8*15 = 120 steps
            STEP(0) STEP(1) STEP(2) STEP(3) STEP(4)
            STEP(5) STEP(6) STEP(7) STEP(8) STEP(9)
            STEP(10) STEP(11) STEP(12) STEP(13) STEP(14)
            t += 15;
        }
        STEP(0) STEP(1) STEP(2) STEP(3) STEP(4) // tail -> 125
        #undef STEP
        #undef SW
        __syncthreads();
    }
    #undef STAGE
    int row = row0 + r;
    int b = row >> 6, i = row & 63;
    zfeat[(size_t)b * 1024 + h * 64 + i] = cnt * (1.0f / (float)T_);
}

// ---------------- G: logits = z_feat @ fc_w.T + fc_b -----------------------
__global__ __launch_bounds__(256) void k_fc(const float* __restrict__ zfeat, const float* __restrict__ fc_w,
                     const float* __restrict__ fc_b, float* __restrict__ logits) {
    int b = blockIdx.x;
    const float* zf = zfeat + (size_t)b * 1024;
    float a0 = 0.f, a1 = 0.f, a2 = 0.f, a3 = 0.f;
    for (int f = threadIdx.x; f < 1024; f += 256) {
        float z = zf[f];
        a0 += z * fc_w[f];
        a1 += z * fc_w[1024 + f];
        a2 += z * fc_w[2048 + f];
        a3 += z * fc_w[3072 + f];
    }
    __shared__ float red[4][256];
    red[0][threadIdx.x] = a0; red[1][threadIdx.x] = a1;
    red[2][threadIdx.x] = a2; red[3][threadIdx.x] = a3;
    __syncthreads();
    for (int off = 128; off > 0; off >>= 1) {
        if (threadIdx.x < off) {
            red[0][threadIdx.x] += red[0][threadIdx.x + off];
            red[1][threadIdx.x] += red[1][threadIdx.x + off];
            red[2][threadIdx.x] += red[2][threadIdx.x + off];
            red[3][threadIdx.x] += red[3][threadIdx.x + off];
        }
        __syncthreads();
    }
    if (threadIdx.x < 4) logits[b * 4 + threadIdx.x] = red[threadIdx.x][0] + fc_b[threadIdx.x];
}

extern "C" void kernel_launch(void* const* d_in, const int* in_sizes, int n_in,
                              void* d_out, int out_size, void* d_ws, size_t ws_size,
                              hipStream_t stream) {
    (void)in_sizes; (void)n_in; (void)out_size; (void)ws_size;
    const float* x      = (const float*)d_in[0];
    const float* q_w    = (const float*)d_in[1];
    const float* q_b    = (const float*)d_in[2];
    const float* k_w    = (const float*)d_in[3];
    const float* k_b    = (const float*)d_in[4];
    const float* conv_w = (const float*)d_in[5];
    const float* bn_g   = (const float*)d_in[7];
    const float* bn_b   = (const float*)d_in[8];
    const float* fc_w   = (const float*)d_in[9];
    const float* fc_b   = (const float*)d_in[10];

    float* out    = (float*)d_out;
    float* logits = out;                        // 128*4
    float* zfeat  = out + 512;                  // 128*1024
    float* wmat   = out + 512 + 131072;         // 128*64*64

    char* ws      = (char*)d_ws;
    float* energy = (float*)ws;                               // 8192 f32
    float* zg     = (float*)(ws + 32768);                     // 8.192M f32
    double* stats = (double*)(ws + 32768 + 32768000);         // 163 f64
    float* scsh   = (float*)(ws + 32768 + 32768000 + 2048);   // 256 f32

    k_energy<<<B_ * N_, 256, 0, stream>>>(x, energy);
    k_attn_softmax<<<B_ * N_, 64, 0, stream>>>(energy, q_w, q_b, k_w, k_b, wmat);
    k_zgcn<<<dim3(8, B_), 256, 0, stream>>>(wmat, x, zg);
    hipMemsetAsync(stats, 0, 163 * sizeof(double), stream);
    k_autocorr<<<256, 256, 0, stream>>>(zg, stats);
    k_edges<<<147, 256, 0, stream>>>(zg, stats);
    k_finalize2<<<1, 64, 0, stream>>>(stats, conv_w, bn_g, bn_b, scsh);
    k_scan<<<B_ * N_ / 16, 256, 0, stream>>>(zg, scsh, zfeat);
    k_fc<<<B_, 256, 0, stream>>>(zfeat, fc_w, fc_b, logits);
}